// Round 1
// 234.305 us; speedup vs baseline: 1.0914x; 1.0914x over previous
//
#include <hip/hip_runtime.h>

#define BB 16
#define MM 32
#define LH 128
#define NSTEPS 15          // K-1
#define SSTR 136
#define NBLK 256           // 2 rows per block, 512 threads (8 waves)
#define FSTR 32            // flag stride in ints (128 B apart)
#define SIDX(row,pxi,ch) (((row)*34 + (pxi))*SSTR + (ch))

typedef __bf16  bf16x8  __attribute__((ext_vector_type(8)));
typedef float   floatx4 __attribute__((ext_vector_type(4)));
typedef unsigned long long ull;

__device__ __forceinline__ float sigm(float x){ return 1.f/(1.f+__expf(-x)); }
__device__ __forceinline__ float tanh_f(float x){ return 1.f - 2.f/(__expf(2.f*x)+1.f); }

__device__ __forceinline__ unsigned short f2bf(float x){
  union { float f; unsigned u; } v; v.f = x;
  unsigned r = v.u + 0x7FFFu + ((v.u >> 16) & 1u);   // RNE
  return (unsigned short)(r >> 16);
}
__device__ __forceinline__ float bf2f(unsigned short u){
  union { unsigned u2; float f; } v; v.u2 = ((unsigned)u) << 16;
  return v.f;
}

// relaxed device-scope ops: complete at coherent point, no L2 wb/inv storms
__device__ __forceinline__ void st_dev(ull* p, ull v){
  __hip_atomic_store(p, v, __ATOMIC_RELAXED, __HIP_MEMORY_SCOPE_AGENT);
}
__device__ __forceinline__ ull ld_dev(ull* p){
  return __hip_atomic_load(p, __ATOMIC_RELAXED, __HIP_MEMORY_SCOPE_AGENT);
}
// poison-safe relaxed spin (0xAAAAAAAA == far behind under signed diff)
__device__ __forceinline__ void wait_flag(int* f, int target){
  while ((int)(__hip_atomic_load(f, __ATOMIC_RELAXED, __HIP_MEMORY_SCOPE_AGENT) - target) < 0){
    __builtin_amdgcn_s_sleep(1);
  }
}
__device__ __forceinline__ void set_flag(int* f, int v){
  // callers __syncthreads() first => vmcnt(0) drained => prior st_dev visible
  __hip_atomic_store(f, v, __ATOMIC_RELAXED, __HIP_MEMORY_SCOPE_AGENT);
}

// Export buffers: expbuf[parity][blk][dir][x] (dir 0 = toL / out-row r0-1,
// dir 1 = toR / out-row r0+2). Each entry packs (tag = 2+s) << 32 | f32 bits,
// so tag+payload travel in one 8B atomic: no separate flag, no vmcnt drain.
// Parity double-buffer is race-free: producer can only overwrite parity p at
// step s+2, which (via its own barriers) requires the consumer to have
// finished its step-s import.
__global__ __launch_bounds__(512, 2) void k_mega(
    const float* __restrict__ mp,   const float* __restrict__ gl,
    const float* __restrict__ W_hid,const float* __restrict__ b_hid,
    const float* __restrict__ W_h0, const float* __restrict__ b_h0,
    const float* __restrict__ W_c0, const float* __restrict__ b_c0,
    const float* __restrict__ Wf,   const float* __restrict__ bfs,
    const float* __restrict__ wih,  const float* __restrict__ bih,
    const float* __restrict__ Whh,  const float* __restrict__ bhh,
    const float* __restrict__ wpol,
    unsigned short* __restrict__ wc0, unsigned short* __restrict__ wc1,
    unsigned short* __restrict__ whhf, float* __restrict__ bsum,
    unsigned short* __restrict__ wfbF,
    ull* __restrict__ expbuf,
    int* __restrict__ flags, float* __restrict__ out)
{
  __shared__ __attribute__((aligned(16))) unsigned short sH[4*34*SSTR]; // 37 KB
  __shared__ float sInp4[2][4][32];   // [parity][out-row r0-1..r0+2][x]

  int t = threadIdx.x, blk = blockIdx.x;
  int pair = blk & 15, b = blk >> 4;
  int y0 = pair*2;          // first image row of the pair
  int wave = t >> 6, l = t & 63, m16 = l & 15, quad = l >> 4;
  bool hasL = (pair > 0), hasR = (pair < 15);
  int ch = wave*16 + m16;   // this wave's 16-ch tile (per gate / per conv out)

  // ---- phase P: weight prep into fragment-linear bf16 -------------------
  for (int c = blk*512 + t; c < 91904; c += NBLK*512){
    if (c < 73728){
      int which = (c >= 36864) ? 1 : 0;
      int cc = which ? c - 36864 : c;
      int i2 = cc*4, frag = i2 >> 9, rem = i2 & 511, ll = rem >> 3, e0 = rem & 7;
      int kk = frag >> 5, ct = (frag >> 2) & 7, kc = frag & 3;
      int co = ct*16 + (ll & 15), ci0 = kc*32 + ((ll >> 4) << 3) + e0;
      const float* src = which ? W_c0 : W_h0;
      ull v = 0;
      #pragma unroll
      for (int j=0;j<4;j++) v |= (ull)f2bf(src[(kk<<14) + (ci0+j)*128 + co]) << (16*j);
      st_dev((ull*)(which ? wc1 : wc0) + cc, v);
    } else if (c < 90112){
      int cc = c - 73728;
      int i2 = cc*4, frag = i2 >> 9, rem = i2 & 511, ll = rem >> 3, e0 = rem & 7;
      int q = frag >> 5, ct = (frag >> 2) & 7, kc = frag & 3;
      int rw = q*128 + ct*16 + (ll & 15), col = kc*32 + ((ll >> 4) << 3) + e0;
      const float* s4 = Whh + rw*128 + col;
      ull v = 0;
      #pragma unroll
      for (int j=0;j<4;j++) v |= (ull)f2bf(s4[j]) << (16*j);
      st_dev((ull*)whhf + cc, v);
    } else if (c < 90368){
      int cc = c - 90112; int j = cc*2;
      union { float f[2]; ull u; } pv;
      pv.f[0] = bih[j] + bhh[j]; pv.f[1] = bih[j+1] + bhh[j+1];
      st_dev((ull*)bsum + cc, pv.u);
    } else {
      // wf B-fragments: frag = ky*4+kc; cols 0..2 = Wf taps (kx), rest zero
      int cc = c - 90368;
      int i2 = cc*4, frag = i2 >> 9, rem = i2 & 511, ll = rem >> 3, e0 = rem & 7;
      int ky = frag >> 2, kc = frag & 3;
      int n = ll & 15, k0 = kc*32 + ((ll >> 4) << 3) + e0;
      ull v = 0;
      if (n < 3){
        #pragma unroll
        for (int j=0;j<4;j++) v |= (ull)f2bf(Wf[(ky*3 + n)*128 + k0 + j]) << (16*j);
      }
      st_dev((ull*)wfbF + cc, v);
    }
  }
  // zero own export slots (both parities) before the grid sync so no block
  // can ever poll a poisoned/garbage tag
  if (t < 128){
    int p = t >> 6, w2 = t & 63;
    st_dev(expbuf + ((size_t)p*NBLK + blk)*64 + w2, 0);
  }
  __syncthreads();                              // vmcnt drained
  if (t == 0) set_flag(&flags[blk*FSTR], 1);

  // ---- phase H: hid rows y0-1..y0+2 computed REDUNDANTLY into LDS -------
  // (replaces the hidb global exchange; out-of-image rows = zero padding)
  {
    int hch = t & 127, g = t >> 7;    // g = LDS row 0..3
    int y = y0 - 1 + g;               // image row
    bool valid = (y >= 0 && y < MM);
    for (int x = 0; x < MM; x++){
      float acc2 = 0.f;
      if (valid){
        acc2 = b_hid[hch];
        #pragma unroll
        for (int ky=0; ky<3; ky++){
          int yy = y + ky - 1; if (yy < 0 || yy >= MM) continue;
          #pragma unroll
          for (int kx=0; kx<3; kx++){
            int xx = x + kx - 1; if (xx < 0 || xx >= MM) continue;
            int gi = (b*MM + yy)*MM + xx;
            int wb = ((ky*3+kx)*2)*LH + hch;
            acc2 += mp[gi] * W_hid[wb] + gl[gi] * W_hid[wb + LH];
          }
        }
      }
      sH[SIDX(g, x+1, hch)] = f2bf(acc2);
    }
  }
  if (t < 256){   // zero x-halo columns
    int k = t >> 6, col = ((t >> 5) & 1) ? 33 : 0, c4 = t & 31;
    *(ull*)&sH[SIDX(k, col, c4*4)] = 0;
  }
  // grid-wide sync: prepped weights (and export-slot zeros) visible
  if (t < NBLK) wait_flag(&flags[t*FSTR], 1);
  __syncthreads();

  // ---- h0 & c0 convs: M=64 px, this wave's 16 out-ch --------------------
  float c_reg[4][4];        // [mt][r] — persists across all steps
  {
    floatx4 acch[4], accc[4];
    #pragma unroll
    for (int mt=0;mt<4;mt++){ acch[mt] = (floatx4){0.f,0.f,0.f,0.f};
                              accc[mt] = (floatx4){0.f,0.f,0.f,0.f}; }
    #pragma unroll
    for (int kk=0; kk<9; kk++){
      int ky = kk/3, kx = kk%3;
      #pragma unroll
      for (int kc=0; kc<4; kc++){
        int frag = ((kk*8 + wave)*4 + kc);
        bf16x8 b0 = *(const bf16x8*)(wc0 + (frag << 9) + l*8);
        bf16x8 b1 = *(const bf16x8*)(wc1 + (frag << 9) + l*8);
        #pragma unroll
        for (int mt=0; mt<4; mt++){
          bf16x8 a = *(const bf16x8*)&sH[SIDX((mt>>1)+ky, m16 + (mt&1)*16 + kx, kc*32 + quad*8)];
          acch[mt] = __builtin_amdgcn_mfma_f32_16x16x32_bf16(a, b0, acch[mt], 0,0,0);
          accc[mt] = __builtin_amdgcn_mfma_f32_16x16x32_bf16(a, b1, accc[mt], 0,0,0);
        }
      }
    }
    __syncthreads();                      // all conv reads done
    float bh = b_h0[ch], bc = b_c0[ch];
    #pragma unroll
    for (int mt=0; mt<4; mt++)
      #pragma unroll
      for (int r=0; r<4; r++){
        int px = mt*16 + quad*4 + r;      // 0..63
        c_reg[mt][r] = accc[mt][r] + bc;
        sH[SIDX(1+(px>>5), (px&31)+1, ch)] = f2bf(acch[mt][r] + bh);
      }
  }
  // init sInp4 parity-0 for step 0 (own rows get the wf bias, exports 0)
  if (t < 128){
    int sR = t >> 5;
    sInp4[0][sR][t & 31] = (sR == 1 || sR == 2) ? bfs[0] : 0.f;
  }
  __syncthreads();                        // h0 in LDS rows 1,2; sInp4[0] ready

  // W_hh^T fragments (this wave: 16 ch x 4 gates x 4 kc) + epilogue consts
  bf16x8 bfr[4][4];   // [q][kc] — constant across steps
  #pragma unroll
  for (int q=0;q<4;q++)
    #pragma unroll
    for (int kc=0;kc<4;kc++){
      int frag = ((q*8 + wave)*4 + kc);
      bfr[q][kc] = *(const bf16x8*)(whhf + (frag << 9) + l*8);
    }
  // wf-conv wave decomposition: (input own row iiw, kc-pair khp, x-half xh2)
  int iiw = wave & 1, khp = ((wave >> 1) & 1) * 2, xh2 = (wave >> 2) * 16;
  bf16x8 wfBr[3][2];  // [ky][kk2] for this wave's kc-pair
  #pragma unroll
  for (int ky=0;ky<3;ky++)
    #pragma unroll
    for (int kk2=0;kk2<2;kk2++)
      wfBr[ky][kk2] = *(const bf16x8*)(wfbF + (((ky*4 + khp + kk2) << 9) + l*8));
  float wv[4], bs[4];
  #pragma unroll
  for (int q=0;q<4;q++){ int g = q*128 + ch; wv[q] = wih[g]; bs[q] = bsum[g]; }
  float bf0 = bfs[0];

  // ---- 15 LSTM steps ----------------------------------------------------
  for (int s = 0; s < NSTEPS; s++){
    int cur = s & 1;
    float (*sIc)[32] = sInp4[cur];
    float (*sIn)[32] = sInp4[cur ^ 1];

    // P1: wf-conv partials. Term (iiw, ky) -> output row sR = iiw - ky + 2
    // (sR 0 = export to left, 1,2 = own rows, 3 = export to right).
    {
      floatx4 pk0 = (floatx4){0.f,0.f,0.f,0.f};
      floatx4 pk1 = (floatx4){0.f,0.f,0.f,0.f};
      floatx4 pk2 = (floatx4){0.f,0.f,0.f,0.f};
      #pragma unroll
      for (int kk2 = 0; kk2 < 2; kk2++){
        int kc = khp + kk2;
        bf16x8 a = *(const bf16x8*)&sH[SIDX(1 + iiw, xh2 + m16 + 1, kc*32 + quad*8)];
        pk0 = __builtin_amdgcn_mfma_f32_16x16x32_bf16(a, wfBr[0][kk2], pk0, 0,0,0);
        pk1 = __builtin_amdgcn_mfma_f32_16x16x32_bf16(a, wfBr[1][kk2], pk1, 0,0,0);
        pk2 = __builtin_amdgcn_mfma_f32_16x16x32_bf16(a, wfBr[2][kk2], pk2, 0,0,0);
      }
      if (m16 < 3){
        int xb = xh2 + quad*4 + m16 - 1;
        #pragma unroll
        for (int r = 0; r < 4; r++){
          int x = xb + r;
          if (x >= 0 && x < 32){
            atomicAdd(&sIc[iiw + 2][x], pk0[r]);   // ky=0
            atomicAdd(&sIc[iiw + 1][x], pk1[r]);   // ky=1
            atomicAdd(&sIc[iiw    ][x], pk2[r]);   // ky=2
          }
        }
      }
    }
    __syncthreads();                      // B1: all partial rows complete

    // publish exports FIRST (critical path for neighbors); tag rides with data
    if (wave == 0){
      int d = l >> 5, x = l & 31;
      union { float f; unsigned u; } pv;
      pv.f = sIc[d ? 3 : 0][x];
      st_dev(expbuf + ((size_t)cur*NBLK + blk)*64 + l,
             ((ull)(unsigned)(2 + s) << 32) | (ull)pv.u);
    }

    // gates GEMM on own rows (LDS rows 1,2)
    floatx4 acc[4][4];    // [mt][q]
    #pragma unroll
    for (int mt=0;mt<4;mt++)
      #pragma unroll
      for (int q=0;q<4;q++) acc[mt][q] = (floatx4){0.f,0.f,0.f,0.f};
    #pragma unroll
    for (int kc=0; kc<4; kc++){
      bf16x8 a[4];
      #pragma unroll
      for (int mt=0;mt<4;mt++)
        a[mt] = *(const bf16x8*)&sH[SIDX(1+(mt>>1), m16 + (mt&1)*16 + 1, kc*32 + quad*8)];
      #pragma unroll
      for (int q=0; q<4; q++)
        #pragma unroll
        for (int mt=0; mt<4; mt++)
          acc[mt][q] = __builtin_amdgcn_mfma_f32_16x16x32_bf16(a[mt], bfr[q][kc], acc[mt][q], 0,0,0);
    }

    // wave 2: init next-parity sInp4 (its last reader was step s-1 epilogue)
    if (wave == 2){
      #pragma unroll
      for (int j = 0; j < 2; j++){
        int c2 = l + 64*j, sR = c2 >> 5;
        sIn[sR][c2 & 31] = (sR == 1 || sR == 2) ? bf0 : 0.f;
      }
    }
    // wave 1: import neighbor partials (poll on embedded tag, poison-safe)
    if (wave == 1){
      int d = l >> 5, x = l & 31;
      bool ok = d ? hasR : hasL;
      if (ok){
        ull* p = expbuf + ((size_t)cur*NBLK + (blk + (d ? 1 : -1)))*64 + (d ? 0 : 32) + x;
        ull v;
        do { v = ld_dev(p); } while ((int)((unsigned)(v >> 32) - (unsigned)(2 + s)) < 0);
        union { unsigned u; float f; } pv; pv.u = (unsigned)v;
        sIc[1 + d][x] += pv.f;
      }
    }
    __syncthreads();                      // B2: sInp final, GEMM + h_s reads done

    // LSTM pointwise epilogue: h_{s+1} -> LDS rows 1,2 (no global publish)
    #pragma unroll
    for (int mt=0; mt<4; mt++){
      #pragma unroll
      for (int r=0; r<4; r++){
        int px = mt*16 + quad*4 + r;
        float iv = sIc[1 + (px >> 5)][px & 31];
        float pre0 = acc[mt][0][r] + iv*wv[0] + bs[0];
        float pre1 = acc[mt][1][r] + iv*wv[1] + bs[1];
        float pre2 = acc[mt][2][r] + iv*wv[2] + bs[2];
        float pre3 = acc[mt][3][r] + iv*wv[3] + bs[3];
        float ig = sigm(pre0), fg = sigm(pre1), gg = tanh_f(pre2), og = sigm(pre3);
        float cn = fg*c_reg[mt][r] + ig*gg;
        c_reg[mt][r] = cn;
        sH[SIDX(1+(px>>5), (px&31)+1, ch)] = f2bf(og * tanh_f(cn));
      }
    }
    __syncthreads();                      // B3: h_{s+1} visible in LDS
  }

  // ---- policy: logits + 4-way softmax from LDS rows 1,2 -----------------
  {
    int px = t >> 3, s8 = t & 7;
    int base = SIDX(1+(px>>5), (px&31)+1, s8*16);
    uint4 h0v = *(const uint4*)&sH[base];
    uint4 h1v = *(const uint4*)&sH[base + 8];
    float la[4] = {0.f,0.f,0.f,0.f};
    const unsigned short* hu = (const unsigned short*)&h0v;
    #pragma unroll
    for (int e=0;e<8;e++){
      int c = s8*16 + e; float hv2 = bf2f(hu[e]);
      const float* w4 = wpol + c*4;
      la[0]+=hv2*w4[0]; la[1]+=hv2*w4[1]; la[2]+=hv2*w4[2]; la[3]+=hv2*w4[3];
    }
    hu = (const unsigned short*)&h1v;
    #pragma unroll
    for (int e=0;e<8;e++){
      int c = s8*16 + 8 + e; float hv2 = bf2f(hu[e]);
      const float* w4 = wpol + c*4;
      la[0]+=hv2*w4[0]; la[1]+=hv2*w4[1]; la[2]+=hv2*w4[2]; la[3]+=hv2*w4[3];
    }
    #pragma unroll
    for (int a=0;a<4;a++){
      la[a] += __shfl_xor(la[a], 1, 64);
      la[a] += __shfl_xor(la[a], 2, 64);
      la[a] += __shfl_xor(la[a], 4, 64);
    }
    if (s8 == 0){
      int y = y0 + (px>>5), x = px & 31;
      float m = fmaxf(fmaxf(la[0],la[1]),fmaxf(la[2],la[3]));
      float e[4]; float sum = 0.f;
      #pragma unroll
      for (int a=0;a<4;a++){ e[a]=__expf(la[a]-m); sum+=e[a]; }
      float inv = 1.f/sum;
      #pragma unroll
      for (int a=0;a<4;a++){
        int o = ((b*4 + a)*MM + y)*MM + x;
        out[o] = la[a];
        out[65536 + o] = e[a]*inv;
      }
    }
  }
}

extern "C" void kernel_launch(void* const* d_in, const int* in_sizes, int n_in,
                              void* d_out, int out_size, void* d_ws, size_t ws_size,
                              hipStream_t stream){
  const float* mp    = (const float*)d_in[0];
  const float* gl    = (const float*)d_in[1];
  const float* W_hid = (const float*)d_in[2];
  const float* b_hid = (const float*)d_in[3];
  const float* W_h0  = (const float*)d_in[4];
  const float* b_h0  = (const float*)d_in[5];
  const float* W_c0  = (const float*)d_in[6];
  const float* b_c0  = (const float*)d_in[7];
  const float* W_f   = (const float*)d_in[8];
  const float* b_f   = (const float*)d_in[9];
  const float* W_ih  = (const float*)d_in[10];
  const float* b_ih  = (const float*)d_in[11];
  const float* W_hh  = (const float*)d_in[12];
  const float* b_hh  = (const float*)d_in[13];
  const float* W_pol = (const float*)d_in[14];
  float* out = (float*)d_out;

  char* ws = (char*)d_ws;
  unsigned short* whhf  = (unsigned short*)ws;                     // 128 KB
  float*          bsum  = (float*)(ws + (128<<10));                // 4 KB
  unsigned short* wc0   = (unsigned short*)(ws + (132<<10));       // 288 KB
  unsigned short* wc1   = (unsigned short*)(ws + (420<<10));       // 288 KB
  int*            flags = (int*)(ws + (708<<10));                  // 32 KB
  unsigned short* wfbF  = (unsigned short*)(ws + (740<<10));       // 12 KB
  ull*            expbuf= (ull*)(ws + (752<<10));                  // 256 KB

  k_mega<<<NBLK, 512, 0, stream>>>(
      mp, gl, W_hid, b_hid, W_h0, b_h0, W_c0, b_c0, W_f, b_f,
      W_ih, b_ih, W_hh, b_hh, W_pol,
      wc0, wc1, whhf, bsum, wfbF, expbuf, flags, out);
}

// Round 2
// 227.674 us; speedup vs baseline: 1.1232x; 1.0291x over previous
//
#include <hip/hip_runtime.h>

#define MM 32
#define LH 128
#define NSTEPS 15          // K-1
#define SSTR 136
#define NBLK 512           // 1 row per block, 512 threads (8 waves), 2 blocks/CU
#define FSTR 32
#define SIDX(row,pxi,ch) (((row)*34 + (pxi))*SSTR + (ch))

typedef __bf16  bf16x8  __attribute__((ext_vector_type(8)));
typedef float   floatx4 __attribute__((ext_vector_type(4)));
typedef unsigned long long ull;

#define L2E 1.4426950408889634f

__device__ __forceinline__ float ex2(float x){
#if __has_builtin(__builtin_amdgcn_exp2f)
  return __builtin_amdgcn_exp2f(x);
#else
  float r; asm volatile("v_exp_f32 %0, %1\n\ts_nop 0" : "=v"(r) : "v"(x)); return r;
#endif
}
__device__ __forceinline__ float frcp(float x){ return __builtin_amdgcn_rcpf(x); }

__device__ __forceinline__ unsigned short cvt_bf16(float x){
  __bf16 b = (__bf16)x; unsigned short u; __builtin_memcpy(&u, &b, 2); return u;
}
__device__ __forceinline__ float bf2f(unsigned short u){
  union { unsigned u2; float f; } v; v.u2 = ((unsigned)u) << 16;
  return v.f;
}

// relaxed device-scope ops
__device__ __forceinline__ void st_dev(ull* p, ull v){
  __hip_atomic_store(p, v, __ATOMIC_RELAXED, __HIP_MEMORY_SCOPE_AGENT);
}
__device__ __forceinline__ ull ld_dev(ull* p){
  return __hip_atomic_load(p, __ATOMIC_RELAXED, __HIP_MEMORY_SCOPE_AGENT);
}
// poison-safe relaxed spin (0xAAAAAAAA == far behind under signed diff)
__device__ __forceinline__ void wait_flag(int* f, int target){
  while ((int)(__hip_atomic_load(f, __ATOMIC_RELAXED, __HIP_MEMORY_SCOPE_AGENT) - target) < 0){
    __builtin_amdgcn_s_sleep(1);
  }
}
__device__ __forceinline__ void set_flag(int* f, int v){
  __hip_atomic_store(f, v, __ATOMIC_RELAXED, __HIP_MEMORY_SCOPE_AGENT);
}

// Export buffers: expbuf[parity][blk][64]; slots 0..31 = up-export (to row y-1),
// 32..63 = down-export (to row y+1). Entry = (tag=2+s)<<32 | f32 bits — tag and
// payload in one 8B atomic. Parity double-buffer race-free (producer overwrites
// parity p at step s+2 only after consumer finished step s import).
__global__ __launch_bounds__(512, 4) void k_mega(
    const float* __restrict__ mp,   const float* __restrict__ gl,
    const float* __restrict__ W_hid,const float* __restrict__ b_hid,
    const float* __restrict__ W_h0, const float* __restrict__ b_h0,
    const float* __restrict__ W_c0, const float* __restrict__ b_c0,
    const float* __restrict__ Wf,   const float* __restrict__ bfs,
    const float* __restrict__ wih,  const float* __restrict__ bih,
    const float* __restrict__ Whh,  const float* __restrict__ bhh,
    const float* __restrict__ wpol,
    unsigned short* __restrict__ wc0, unsigned short* __restrict__ wc1,
    unsigned short* __restrict__ whhf, float* __restrict__ bsum,
    unsigned short* __restrict__ wfbF,
    ull* __restrict__ expbuf,
    int* __restrict__ flags, float* __restrict__ out)
{
  __shared__ __attribute__((aligned(16))) unsigned short sH[3*34*SSTR]; // 27.7 KB
  __shared__ float sInp4[2][3][32];   // [parity][out-row y-1,y,y+1][x]

  int t = threadIdx.x, blk = blockIdx.x;
  int y = blk & 31, b = blk >> 5;     // own image row, image index
  int wave = t >> 6, l = t & 63, m16 = l & 15, quad = l >> 4;
  bool hasU = (y > 0), hasD = (y < 31);
  int ch = wave*16 + m16;             // this wave's 16-ch tile

  // ---- phase P: weight prep into fragment-linear bf16 -------------------
  // W_hh rows are prescaled per-gate by SC[q] (folds log2e into exp2 args).
  for (int c = blk*512 + t; c < 91904; c += NBLK*512){
    if (c < 73728){
      int which = (c >= 36864) ? 1 : 0;
      int cc = which ? c - 36864 : c;
      int i2 = cc*4, frag = i2 >> 9, rem = i2 & 511, ll = rem >> 3, e0 = rem & 7;
      int kk = frag >> 5, ct = (frag >> 2) & 7, kc = frag & 3;
      int co = ct*16 + (ll & 15), ci0 = kc*32 + ((ll >> 4) << 3) + e0;
      const float* src = which ? W_c0 : W_h0;
      ull v = 0;
      #pragma unroll
      for (int j=0;j<4;j++) v |= (ull)cvt_bf16(src[(kk<<14) + (ci0+j)*128 + co]) << (16*j);
      st_dev((ull*)(which ? wc1 : wc0) + cc, v);
    } else if (c < 90112){
      int cc = c - 73728;
      int i2 = cc*4, frag = i2 >> 9, rem = i2 & 511, ll = rem >> 3, e0 = rem & 7;
      int q = frag >> 5, ct = (frag >> 2) & 7, kc = frag & 3;
      float scq = (q == 2) ? (2.f*L2E) : (-L2E);
      int rw = q*128 + ct*16 + (ll & 15), col = kc*32 + ((ll >> 4) << 3) + e0;
      const float* s4 = Whh + rw*128 + col;
      ull v = 0;
      #pragma unroll
      for (int j=0;j<4;j++) v |= (ull)cvt_bf16(s4[j]*scq) << (16*j);
      st_dev((ull*)whhf + cc, v);
    } else if (c < 90368){
      int cc = c - 90112; int j = cc*2;
      union { float f[2]; ull u; } pv;
      pv.f[0] = bih[j] + bhh[j]; pv.f[1] = bih[j+1] + bhh[j+1];
      st_dev((ull*)bsum + cc, pv.u);
    } else {
      // wf B-fragments: frag = ky*4+kc; cols 0..2 = Wf taps (kx), rest zero
      int cc = c - 90368;
      int i2 = cc*4, frag = i2 >> 9, rem = i2 & 511, ll = rem >> 3, e0 = rem & 7;
      int ky = frag >> 2, kc = frag & 3;
      int n = ll & 15, k0 = kc*32 + ((ll >> 4) << 3) + e0;
      ull v = 0;
      if (n < 3){
        #pragma unroll
        for (int j=0;j<4;j++) v |= (ull)cvt_bf16(Wf[(ky*3 + n)*128 + k0 + j]) << (16*j);
      }
      st_dev((ull*)wfbF + cc, v);
    }
  }
  // zero own export slots (both parities): poll tags always defined
  if (t < 128){
    int p = t >> 6, w2 = t & 63;
    st_dev(expbuf + ((size_t)p*NBLK + blk)*64 + w2, 0);
  }
  __syncthreads();                              // vmcnt drained
  if (t == 0) set_flag(&flags[blk*FSTR], 1);

  // ---- phase H: hid rows y-1..y+1 computed redundantly into LDS ---------
  {
    int hch = t & 127, grp = t >> 7;            // grp 0..3, 24 row-px each
    float wz0[9], wz1[9];
    #pragma unroll
    for (int kk=0;kk<9;kk++){ wz0[kk] = W_hid[(kk*2)*LH + hch];
                              wz1[kk] = W_hid[(kk*2+1)*LH + hch]; }
    float bh = b_hid[hch];
    for (int i = 0; i < 24; i++){
      int rp = grp*24 + i, row = rp >> 5, x = rp & 31;
      int yi = y - 1 + row;
      float acc2 = 0.f;
      if (yi >= 0 && yi < MM){
        acc2 = bh;
        #pragma unroll
        for (int ky=0; ky<3; ky++){
          int yy = yi + ky - 1; if (yy < 0 || yy >= MM) continue;
          #pragma unroll
          for (int kx=0; kx<3; kx++){
            int xx = x + kx - 1; if (xx < 0 || xx >= MM) continue;
            int gi = (b*MM + yy)*MM + xx;
            acc2 += mp[gi]*wz0[ky*3+kx] + gl[gi]*wz1[ky*3+kx];
          }
        }
      }
      sH[SIDX(row, x+1, hch)] = cvt_bf16(acc2);
    }
  }
  if (t < 192){   // zero x-halo columns, rows 0..2
    int k = t >> 6, col = ((t >> 5) & 1) ? 33 : 0, c4 = t & 31;
    *(ull*)&sH[SIDX(k, col, c4*4)] = 0;
  }
  // grid sync: only prepper blocks' flags (blk<=179) — no full-residency req
  if (t < 180) wait_flag(&flags[t*FSTR], 1);
  __syncthreads();

  // ---- h0 & c0 convs: own row (32 px), this wave's 16 out-ch ------------
  float c_reg[2][4];        // [mt][r] — persists across all steps
  {
    floatx4 acch[2], accc[2];
    #pragma unroll
    for (int mt=0;mt<2;mt++){ acch[mt] = (floatx4){0.f,0.f,0.f,0.f};
                              accc[mt] = (floatx4){0.f,0.f,0.f,0.f}; }
    #pragma unroll
    for (int kk=0; kk<9; kk++){
      int ky = kk/3, kx = kk%3;
      #pragma unroll
      for (int kc=0; kc<4; kc++){
        int frag = ((kk*8 + wave)*4 + kc);
        bf16x8 b0 = *(const bf16x8*)(wc0 + (frag << 9) + l*8);
        bf16x8 b1 = *(const bf16x8*)(wc1 + (frag << 9) + l*8);
        #pragma unroll
        for (int mt=0; mt<2; mt++){
          bf16x8 a = *(const bf16x8*)&sH[SIDX(ky, m16 + mt*16 + kx, kc*32 + quad*8)];
          acch[mt] = __builtin_amdgcn_mfma_f32_16x16x32_bf16(a, b0, acch[mt], 0,0,0);
          accc[mt] = __builtin_amdgcn_mfma_f32_16x16x32_bf16(a, b1, accc[mt], 0,0,0);
        }
      }
    }
    __syncthreads();                      // all conv reads done
    float bh = b_h0[ch], bc = b_c0[ch];
    #pragma unroll
    for (int mt=0; mt<2; mt++)
      #pragma unroll
      for (int r=0; r<4; r++){
        int px = mt*16 + quad*4 + r;      // 0..31
        c_reg[mt][r] = accc[mt][r] + bc;
        sH[SIDX(1, px+1, ch)] = cvt_bf16(acch[mt][r] + bh);
      }
  }
  // init sInp4 parity-0 (own row gets wf bias, export rows 0)
  if (t < 96){
    int sR = t >> 5;
    sInp4[0][sR][t & 31] = (sR == 1) ? bfs[0] : 0.f;
  }
  __syncthreads();                        // h0 in LDS row 1; sInp4[0] ready

  // wf-conv wave decomposition: kc = wave&3, x-half = wave>>2
  int kcw = wave & 3, xh = (wave >> 2) * 16;
  bf16x8 wfBr[3];
  #pragma unroll
  for (int ky=0;ky<3;ky++)
    wfBr[ky] = *(const bf16x8*)(wfbF + (((ky*4 + kcw) << 9) + l*8));
  float wv[4], bs[4];
  #pragma unroll
  for (int q=0;q<4;q++){
    float scq = (q == 2) ? (2.f*L2E) : (-L2E);
    int g = q*128 + ch;
    wv[q] = wih[g]*scq; bs[q] = bsum[g]*scq;
  }
  float bf0 = bfs[0];

  // ---- 15 LSTM steps ----------------------------------------------------
  for (int s = 0; s < NSTEPS; s++){
    int cur = s & 1;
    float (*sIc)[32] = sInp4[cur];
    float (*sIn)[32] = sInp4[cur ^ 1];

    // P1: wf-conv partials from own row; ky=0 -> row y+1 (sIc[2]),
    // ky=1 -> own (sIc[1]), ky=2 -> row y-1 (sIc[0])
    {
      bf16x8 a = *(const bf16x8*)&sH[SIDX(1, xh + m16 + 1, kcw*32 + quad*8)];
      floatx4 pk0 = (floatx4){0.f,0.f,0.f,0.f};
      floatx4 pk1 = (floatx4){0.f,0.f,0.f,0.f};
      floatx4 pk2 = (floatx4){0.f,0.f,0.f,0.f};
      pk0 = __builtin_amdgcn_mfma_f32_16x16x32_bf16(a, wfBr[0], pk0, 0,0,0);
      pk1 = __builtin_amdgcn_mfma_f32_16x16x32_bf16(a, wfBr[1], pk1, 0,0,0);
      pk2 = __builtin_amdgcn_mfma_f32_16x16x32_bf16(a, wfBr[2], pk2, 0,0,0);
      if (m16 < 3){
        int xb = xh + quad*4 + m16 - 1;
        #pragma unroll
        for (int r = 0; r < 4; r++){
          int x = xb + r;
          if (x >= 0 && x < 32){
            atomicAdd(&sIc[2][x], pk0[r]);
            atomicAdd(&sIc[1][x], pk1[r]);
            atomicAdd(&sIc[0][x], pk2[r]);
          }
        }
      }
    }
    __syncthreads();                      // B1: partial rows complete

    // publish exports first (neighbors' critical path); tag rides with data
    if (wave == 0){
      int d = l >> 5, x = l & 31;
      union { float f; unsigned u; } pv;
      pv.f = sIc[d ? 2 : 0][x];
      st_dev(expbuf + ((size_t)cur*NBLK + blk)*64 + l,
             ((ull)(unsigned)(2 + s) << 32) | (ull)pv.u);
    }

    // gates GEMM on own row; B streamed from L2-hot whhf (anti-hoist ptr)
    ull wa = (ull)whhf;
    asm volatile("" : "+v"(wa));
    const unsigned short* wp = (const unsigned short*)wa;
    floatx4 acc[2][4];    // [mt][q]
    #pragma unroll
    for (int mt=0;mt<2;mt++)
      #pragma unroll
      for (int q=0;q<4;q++) acc[mt][q] = (floatx4){0.f,0.f,0.f,0.f};
    #pragma unroll
    for (int kc=0; kc<4; kc++){
      bf16x8 a0 = *(const bf16x8*)&sH[SIDX(1, m16 + 1,  kc*32 + quad*8)];
      bf16x8 a1 = *(const bf16x8*)&sH[SIDX(1, m16 + 17, kc*32 + quad*8)];
      #pragma unroll
      for (int q=0; q<4; q++){
        bf16x8 bq = *(const bf16x8*)(wp + ((q*32 + wave*4 + kc) << 9) + l*8);
        acc[0][q] = __builtin_amdgcn_mfma_f32_16x16x32_bf16(a0, bq, acc[0][q], 0,0,0);
        acc[1][q] = __builtin_amdgcn_mfma_f32_16x16x32_bf16(a1, bq, acc[1][q], 0,0,0);
      }
    }

    // wave 2: init next-parity sInp4
    if (wave == 2){
      #pragma unroll
      for (int j = 0; j < 2; j++){
        int c2 = l + 64*j;
        if (c2 < 96){ int sR = c2 >> 5; sIn[sR][c2 & 31] = (sR == 1) ? bf0 : 0.f; }
      }
    }
    // wave 1: import neighbor partials into own row (single writer per x)
    if (wave == 1 && l < 32){
      int x = l;
      float addv = 0.f;
      if (hasU){
        ull* p = expbuf + ((size_t)cur*NBLK + blk - 1)*64 + 32 + x;  // their down-export
        ull v;
        do { v = ld_dev(p); } while ((int)((unsigned)(v >> 32) - (unsigned)(2 + s)) < 0);
        union { unsigned u; float f; } pv; pv.u = (unsigned)v; addv += pv.f;
      }
      if (hasD){
        ull* p = expbuf + ((size_t)cur*NBLK + blk + 1)*64 + x;       // their up-export
        ull v;
        do { v = ld_dev(p); } while ((int)((unsigned)(v >> 32) - (unsigned)(2 + s)) < 0);
        union { unsigned u; float f; } pv; pv.u = (unsigned)v; addv += pv.f;
      }
      sIc[1][x] += addv;
    }
    __syncthreads();                      // B2: sInp final, row reads done

    // LSTM pointwise epilogue (exp2-form, prescaled gates; rcp not IEEE div)
    #pragma unroll
    for (int mt=0; mt<2; mt++){
      #pragma unroll
      for (int r=0; r<4; r++){
        int px = mt*16 + quad*4 + r;
        float iv = sIc[1][px];
        float p0 = acc[mt][0][r] + iv*wv[0] + bs[0];
        float p1 = acc[mt][1][r] + iv*wv[1] + bs[1];
        float p2 = acc[mt][2][r] + iv*wv[2] + bs[2];
        float p3 = acc[mt][3][r] + iv*wv[3] + bs[3];
        float ig = frcp(1.f + ex2(p0));
        float fg = frcp(1.f + ex2(p1));
        float gg = 1.f - 2.f*frcp(1.f + ex2(p2));
        float og = frcp(1.f + ex2(p3));
        float cn = fg*c_reg[mt][r] + ig*gg;
        c_reg[mt][r] = cn;
        float th = 1.f - 2.f*frcp(1.f + ex2((2.f*L2E)*cn));
        sH[SIDX(1, px+1, ch)] = cvt_bf16(og*th);
      }
    }
    __syncthreads();                      // B3: h_{s+1} visible in LDS
  }

  // ---- policy: logits + 4-way softmax from LDS row 1 --------------------
  {
    int px = t >> 4, s16 = t & 15;
    int base = SIDX(1, px+1, s16*8);
    uint4 h0v = *(const uint4*)&sH[base];
    float la[4] = {0.f,0.f,0.f,0.f};
    const unsigned short* hu = (const unsigned short*)&h0v;
    #pragma unroll
    for (int e=0;e<8;e++){
      int c = s16*8 + e; float hv2 = bf2f(hu[e]);
      const float* w4 = wpol + c*4;
      la[0]+=hv2*w4[0]; la[1]+=hv2*w4[1]; la[2]+=hv2*w4[2]; la[3]+=hv2*w4[3];
    }
    #pragma unroll
    for (int a=0;a<4;a++){
      la[a] += __shfl_xor(la[a], 1, 64);
      la[a] += __shfl_xor(la[a], 2, 64);
      la[a] += __shfl_xor(la[a], 4, 64);
      la[a] += __shfl_xor(la[a], 8, 64);
    }
    if (s16 == 0){
      float m = fmaxf(fmaxf(la[0],la[1]),fmaxf(la[2],la[3]));
      float e[4]; float sum = 0.f;
      #pragma unroll
      for (int a=0;a<4;a++){ e[a]=__expf(la[a]-m); sum+=e[a]; }
      float inv = frcp(sum);
      #pragma unroll
      for (int a=0;a<4;a++){
        int o = ((b*4 + a)*MM + y)*MM + px;
        out[o] = la[a];
        out[65536 + o] = e[a]*inv;
      }
    }
  }
}

extern "C" void kernel_launch(void* const* d_in, const int* in_sizes, int n_in,
                              void* d_out, int out_size, void* d_ws, size_t ws_size,
                              hipStream_t stream){
  const float* mp    = (const float*)d_in[0];
  const float* gl    = (const float*)d_in[1];
  const float* W_hid = (const float*)d_in[2];
  const float* b_hid = (const float*)d_in[3];
  const float* W_h0  = (const float*)d_in[4];
  const float* b_h0  = (const float*)d_in[5];
  const float* W_c0  = (const float*)d_in[6];
  const float* b_c0  = (const float*)d_in[7];
  const float* W_f   = (const float*)d_in[8];
  const float* b_f   = (const float*)d_in[9];
  const float* W_ih  = (const float*)d_in[10];
  const float* b_ih  = (const float*)d_in[11];
  const float* W_hh  = (const float*)d_in[12];
  const float* b_hh  = (const float*)d_in[13];
  const float* W_pol = (const float*)d_in[14];
  float* out = (float*)d_out;

  char* ws = (char*)d_ws;
  unsigned short* whhf  = (unsigned short*)ws;                     // 128 KB
  float*          bsum  = (float*)(ws + (128<<10));                // 4 KB
  unsigned short* wc0   = (unsigned short*)(ws + (132<<10));       // 288 KB
  unsigned short* wc1   = (unsigned short*)(ws + (420<<10));       // 288 KB
  unsigned short* wfbF  = (unsigned short*)(ws + (708<<10));       // 12 KB
  int*            flags = (int*)(ws + (720<<10));                  // 64 KB
  ull*            expbuf= (ull*)(ws + (784<<10));                  // 512 KB

  k_mega<<<NBLK, 512, 0, stream>>>(
      mp, gl, W_hid, b_hid, W_h0, b_h0, W_c0, b_c0, W_f, b_f,
      W_ih, b_ih, W_hh, b_hh, W_pol,
      wc0, wc1, whhf, bsum, wfbF, expbuf, flags, out);
}

// Round 3
// 181.800 us; speedup vs baseline: 1.4066x; 1.2523x over previous
//
#include <hip/hip_runtime.h>

#define MM 32
#define LH 128
#define NSTEPS 15          // K-1
#define SSTR 136
#define NBLK 512           // 1 row per block, 512 threads (8 waves), 2 blocks/CU
#define FSTR 32
#define SIDX(row,pxi,ch) (((row)*34 + (pxi))*SSTR + (ch))

typedef __bf16  bf16x8  __attribute__((ext_vector_type(8)));
typedef float   floatx4 __attribute__((ext_vector_type(4)));
typedef unsigned long long ull;

#define L2E 1.4426950408889634f

__device__ __forceinline__ float ex2(float x){
#if __has_builtin(__builtin_amdgcn_exp2f)
  return __builtin_amdgcn_exp2f(x);
#else
  float r; asm volatile("v_exp_f32 %0, %1\n\ts_nop 0" : "=v"(r) : "v"(x)); return r;
#endif
}
__device__ __forceinline__ float frcp(float x){ return __builtin_amdgcn_rcpf(x); }

__device__ __forceinline__ unsigned short cvt_bf16(float x){
  __bf16 b = (__bf16)x; unsigned short u; __builtin_memcpy(&u, &b, 2); return u;
}
__device__ __forceinline__ float bf2f(unsigned short u){
  union { unsigned u2; float f; } v; v.u2 = ((unsigned)u) << 16;
  return v.f;
}

// relaxed device-scope ops
__device__ __forceinline__ void st_dev(ull* p, ull v){
  __hip_atomic_store(p, v, __ATOMIC_RELAXED, __HIP_MEMORY_SCOPE_AGENT);
}
__device__ __forceinline__ ull ld_dev(ull* p){
  return __hip_atomic_load(p, __ATOMIC_RELAXED, __HIP_MEMORY_SCOPE_AGENT);
}
// poison-safe relaxed spin (0xAAAAAAAA == far behind under signed diff)
__device__ __forceinline__ void wait_flag(int* f, int target){
  while ((int)(__hip_atomic_load(f, __ATOMIC_RELAXED, __HIP_MEMORY_SCOPE_AGENT) - target) < 0){
    __builtin_amdgcn_s_sleep(1);
  }
}
__device__ __forceinline__ void set_flag(int* f, int v){
  __hip_atomic_store(f, v, __ATOMIC_RELAXED, __HIP_MEMORY_SCOPE_AGENT);
}

// Export buffers: expbuf[parity][blk][64]; slots 0..31 = up-export (conv
// partial for row y-1), 32..63 = down-export (row y+1). Entry packs
// (tag = 2+s)<<32 | f32 bits: tag+payload in one 8B atomic. Parity
// double-buffer race-free: producer overwrites parity p at step s+2 only
// after its step-s+1 import, which requires the consumer past its step-s B2.
__global__ __launch_bounds__(512, 4) void k_mega(
    const float* __restrict__ mp,   const float* __restrict__ gl,
    const float* __restrict__ W_hid,const float* __restrict__ b_hid,
    const float* __restrict__ W_h0, const float* __restrict__ b_h0,
    const float* __restrict__ W_c0, const float* __restrict__ b_c0,
    const float* __restrict__ Wf,   const float* __restrict__ bfs,
    const float* __restrict__ wih,  const float* __restrict__ bih,
    const float* __restrict__ Whh,  const float* __restrict__ bhh,
    const float* __restrict__ wpol,
    unsigned short* __restrict__ wc0, unsigned short* __restrict__ wc1,
    unsigned short* __restrict__ whhf, float* __restrict__ bsum,
    unsigned short* __restrict__ wfbF,
    ull* __restrict__ expbuf,
    int* __restrict__ flags, float* __restrict__ out)
{
  __shared__ __attribute__((aligned(16))) unsigned short sH[3*34*SSTR]; // 27.7 KB
  __shared__ float sCv[3][3][36];     // per-conv-wave tap scratch (wave 0..2)
  __shared__ float sOwn[32];          // own-row conv input (bias folded)
  __shared__ float sImp[2][32];       // imported neighbor partials (up,down)

  int t = threadIdx.x, blk = blockIdx.x;
  int y = blk & 31, b = blk >> 5;     // own image row, image index
  int wave = t >> 6, l = t & 63, m16 = l & 15, quad = l >> 4;
  bool hasU = (y > 0), hasD = (y < 31);
  int ch = wave*16 + m16;             // this wave's 16-ch tile

  // ---- phase P: weight prep into fragment-linear bf16 -------------------
  // W_hh rows are prescaled per-gate by SC[q] (folds log2e into exp2 args).
  for (int c = blk*512 + t; c < 91904; c += NBLK*512){
    if (c < 73728){
      int which = (c >= 36864) ? 1 : 0;
      int cc = which ? c - 36864 : c;
      int i2 = cc*4, frag = i2 >> 9, rem = i2 & 511, ll = rem >> 3, e0 = rem & 7;
      int kk = frag >> 5, ct = (frag >> 2) & 7, kc = frag & 3;
      int co = ct*16 + (ll & 15), ci0 = kc*32 + ((ll >> 4) << 3) + e0;
      const float* src = which ? W_c0 : W_h0;
      ull v = 0;
      #pragma unroll
      for (int j=0;j<4;j++) v |= (ull)cvt_bf16(src[(kk<<14) + (ci0+j)*128 + co]) << (16*j);
      st_dev((ull*)(which ? wc1 : wc0) + cc, v);
    } else if (c < 90112){
      int cc = c - 73728;
      int i2 = cc*4, frag = i2 >> 9, rem = i2 & 511, ll = rem >> 3, e0 = rem & 7;
      int q = frag >> 5, ct = (frag >> 2) & 7, kc = frag & 3;
      float scq = (q == 2) ? (2.f*L2E) : (-L2E);
      int rw = q*128 + ct*16 + (ll & 15), col = kc*32 + ((ll >> 4) << 3) + e0;
      const float* s4 = Whh + rw*128 + col;
      ull v = 0;
      #pragma unroll
      for (int j=0;j<4;j++) v |= (ull)cvt_bf16(s4[j]*scq) << (16*j);
      st_dev((ull*)whhf + cc, v);
    } else if (c < 90368){
      int cc = c - 90112; int j = cc*2;
      union { float f[2]; ull u; } pv;
      pv.f[0] = bih[j] + bhh[j]; pv.f[1] = bih[j+1] + bhh[j+1];
      st_dev((ull*)bsum + cc, pv.u);
    } else {
      // wf B-fragments: frag = ky*4+kc; cols 0..2 = Wf taps (kx), rest zero
      int cc = c - 90368;
      int i2 = cc*4, frag = i2 >> 9, rem = i2 & 511, ll = rem >> 3, e0 = rem & 7;
      int ky = frag >> 2, kc = frag & 3;
      int n = ll & 15, k0 = kc*32 + ((ll >> 4) << 3) + e0;
      ull v = 0;
      if (n < 3){
        #pragma unroll
        for (int j=0;j<4;j++) v |= (ull)cvt_bf16(Wf[(ky*3 + n)*128 + k0 + j]) << (16*j);
      }
      st_dev((ull*)wfbF + cc, v);
    }
  }
  // zero own export slots (both parities): poll tags always defined
  if (t < 128){
    int p = t >> 6, w2 = t & 63;
    st_dev(expbuf + ((size_t)p*NBLK + blk)*64 + w2, 0);
  }
  __syncthreads();                              // vmcnt drained
  if (t == 0) set_flag(&flags[blk*FSTR], 1);

  // ---- phase H: hid rows y-1..y+1 computed redundantly into LDS ---------
  {
    int hch = t & 127, grp = t >> 7;            // grp 0..3, 24 row-px each
    float wz0[9], wz1[9];
    #pragma unroll
    for (int kk=0;kk<9;kk++){ wz0[kk] = W_hid[(kk*2)*LH + hch];
                              wz1[kk] = W_hid[(kk*2+1)*LH + hch]; }
    float bh = b_hid[hch];
    for (int i = 0; i < 24; i++){
      int rp = grp*24 + i, row = rp >> 5, x = rp & 31;
      int yi = y - 1 + row;
      float acc2 = 0.f;
      if (yi >= 0 && yi < MM){
        acc2 = bh;
        #pragma unroll
        for (int ky=0; ky<3; ky++){
          int yy = yi + ky - 1; if (yy < 0 || yy >= MM) continue;
          #pragma unroll
          for (int kx=0; kx<3; kx++){
            int xx = x + kx - 1; if (xx < 0 || xx >= MM) continue;
            int gi = (b*MM + yy)*MM + xx;
            acc2 += mp[gi]*wz0[ky*3+kx] + gl[gi]*wz1[ky*3+kx];
          }
        }
      }
      sH[SIDX(row, x+1, hch)] = cvt_bf16(acc2);
    }
  }
  if (t < 192){   // zero x-halo columns, rows 0..2
    int k = t >> 6, col = ((t >> 5) & 1) ? 33 : 0, c4 = t & 31;
    *(ull*)&sH[SIDX(k, col, c4*4)] = 0;
  }
  // zero the two never-written tap-scratch entries per conv wave (once)
  if (t < 3){ sCv[t][0][32] = 0.f; sCv[t][2][1] = 0.f; }
  // grid sync: only prepper blocks' flags (blk<=179) — no full-residency req
  if (t < 180) wait_flag(&flags[t*FSTR], 1);
  __syncthreads();

  // ---- h0 & c0 convs: own row (32 px), this wave's 16 out-ch ------------
  float c_reg[2][4];        // [mt][r] — persists across all steps
  {
    floatx4 acch[2], accc[2];
    #pragma unroll
    for (int mt=0;mt<2;mt++){ acch[mt] = (floatx4){0.f,0.f,0.f,0.f};
                              accc[mt] = (floatx4){0.f,0.f,0.f,0.f}; }
    #pragma unroll
    for (int kk=0; kk<9; kk++){
      int ky = kk/3, kx = kk%3;
      #pragma unroll
      for (int kc=0; kc<4; kc++){
        int frag = ((kk*8 + wave)*4 + kc);
        bf16x8 b0 = *(const bf16x8*)(wc0 + (frag << 9) + l*8);
        bf16x8 b1 = *(const bf16x8*)(wc1 + (frag << 9) + l*8);
        #pragma unroll
        for (int mt=0; mt<2; mt++){
          bf16x8 a = *(const bf16x8*)&sH[SIDX(ky, m16 + mt*16 + kx, kc*32 + quad*8)];
          acch[mt] = __builtin_amdgcn_mfma_f32_16x16x32_bf16(a, b0, acch[mt], 0,0,0);
          accc[mt] = __builtin_amdgcn_mfma_f32_16x16x32_bf16(a, b1, accc[mt], 0,0,0);
        }
      }
    }
    __syncthreads();                      // all conv reads done
    float bh = b_h0[ch], bc = b_c0[ch];
    #pragma unroll
    for (int mt=0; mt<2; mt++)
      #pragma unroll
      for (int r=0; r<4; r++){
        int px = mt*16 + quad*4 + r;      // 0..31
        c_reg[mt][r] = accc[mt][r] + bc;
        sH[SIDX(1, px+1, ch)] = cvt_bf16(acch[mt][r] + bh);
      }
  }
  __syncthreads();                        // h0 in LDS row 1

  // conv-wave role fragments: wave0 = up-export (ky=2), wave1 = down (ky=0),
  // wave2 = own row (ky=1); all 4 kc per wave (kc-sum via MFMA accumulation)
  int cky = (wave == 0) ? 2 : ((wave == 1) ? 0 : 1);
  bf16x8 wfC[4];
  if (wave < 3){
    #pragma unroll
    for (int kc=0;kc<4;kc++)
      wfC[kc] = *(const bf16x8*)(wfbF + (((cky*4 + kc) << 9) + l*8));
  }
  float wv[4], bs[4];
  #pragma unroll
  for (int q=0;q<4;q++){
    float scq = (q == 2) ? (2.f*L2E) : (-L2E);
    int g = q*128 + ch;
    wv[q] = wih[g]*scq; bs[q] = bsum[g]*scq;
  }
  float bf0 = bfs[0];

  // ---- 15 LSTM steps ----------------------------------------------------
  for (int s = 0; s < NSTEPS; s++){
    int cur = s & 1;

    // P1 (waves 0-2): whole conv row in one wave -> tap-sum in private LDS
    // scratch -> publish/store IMMEDIATELY (no barrier before publish).
    bool doRole = (wave == 2) || (wave == 0 && hasU) || (wave == 1 && hasD);
    if (wave < 3 && doRole){
      floatx4 p0 = (floatx4){0.f,0.f,0.f,0.f};
      floatx4 p1 = (floatx4){0.f,0.f,0.f,0.f};
      #pragma unroll
      for (int kc=0;kc<4;kc++){
        bf16x8 aL = *(const bf16x8*)&sH[SIDX(1, m16 + 1,  kc*32 + quad*8)];
        bf16x8 aR = *(const bf16x8*)&sH[SIDX(1, m16 + 17, kc*32 + quad*8)];
        p0 = __builtin_amdgcn_mfma_f32_16x16x32_bf16(aL, wfC[kc], p0, 0,0,0);
        p1 = __builtin_amdgcn_mfma_f32_16x16x32_bf16(aR, wfC[kc], p1, 0,0,0);
      }
      // P[px][tap] -> scratch[tap][px+tap]; all taps of out[x] at index x+1
      if (m16 < 3){
        #pragma unroll
        for (int r=0;r<4;r++){
          sCv[wave][m16][quad*4 + r + m16]      = p0[r];
          sCv[wave][m16][16 + quad*4 + r + m16] = p1[r];
        }
      }
      __asm__ __volatile__("" ::: "memory");  // keep write->read order (same-wave DS is in-order)
      if (l < 32){
        float v = sCv[wave][0][l+1] + sCv[wave][1][l+1] + sCv[wave][2][l+1];
        if (wave == 2){
          sOwn[l] = bf0 + v;
        } else {
          union { float f; unsigned u; } pv; pv.f = v;
          st_dev(expbuf + ((size_t)cur*NBLK + blk)*64 + (wave == 1 ? 32 : 0) + l,
                 ((ull)(unsigned)(2 + s) << 32) | (ull)pv.u);
        }
      }
    }

    // gates GEMM on own row; B streamed from L2-hot whhf (anti-hoist ptr)
    ull wa = (ull)whhf;
    asm volatile("" : "+v"(wa));
    const unsigned short* wp = (const unsigned short*)wa;
    floatx4 acc[2][4];    // [mt][q]
    #pragma unroll
    for (int mt=0;mt<2;mt++)
      #pragma unroll
      for (int q=0;q<4;q++) acc[mt][q] = (floatx4){0.f,0.f,0.f,0.f};
    #pragma unroll
    for (int kc=0; kc<4; kc++){
      bf16x8 a0 = *(const bf16x8*)&sH[SIDX(1, m16 + 1,  kc*32 + quad*8)];
      bf16x8 a1 = *(const bf16x8*)&sH[SIDX(1, m16 + 17, kc*32 + quad*8)];
      #pragma unroll
      for (int q=0; q<4; q++){
        bf16x8 bq = *(const bf16x8*)(wp + ((q*32 + wave*4 + kc) << 9) + l*8);
        acc[0][q] = __builtin_amdgcn_mfma_f32_16x16x32_bf16(a0, bq, acc[0][q], 0,0,0);
        acc[1][q] = __builtin_amdgcn_mfma_f32_16x16x32_bf16(a1, bq, acc[1][q], 0,0,0);
      }
    }

    // wave 3: import both neighbors IN PARALLEL (lane-split spin)
    if (wave == 3){
      int d = l >> 5, x = l & 31;
      bool ok = d ? hasD : hasU;
      float v = 0.f;
      if (ok){
        ull* p = expbuf + ((size_t)cur*NBLK + (d ? blk+1 : blk-1))*64 + (d ? 0 : 32) + x;
        ull vv;
        do { vv = ld_dev(p); } while ((int)((unsigned)(vv >> 32) - (unsigned)(2 + s)) < 0);
        union { unsigned u; float f; } pv; pv.u = (unsigned)vv; v = pv.f;
      }
      sImp[d][x] = v;
    }
    __syncthreads();                      // B2: sOwn/sImp final, row reads done

    // LSTM pointwise epilogue (exp2-form, prescaled gates; rcp not IEEE div)
    #pragma unroll
    for (int mt=0; mt<2; mt++){
      #pragma unroll
      for (int r=0; r<4; r++){
        int px = mt*16 + quad*4 + r;
        float iv = sOwn[px] + sImp[0][px] + sImp[1][px];
        float p0 = acc[mt][0][r] + iv*wv[0] + bs[0];
        float p1 = acc[mt][1][r] + iv*wv[1] + bs[1];
        float p2 = acc[mt][2][r] + iv*wv[2] + bs[2];
        float p3 = acc[mt][3][r] + iv*wv[3] + bs[3];
        float ig = frcp(1.f + ex2(p0));
        float fg = frcp(1.f + ex2(p1));
        float gg = 1.f - 2.f*frcp(1.f + ex2(p2));
        float og = frcp(1.f + ex2(p3));
        float cn = fg*c_reg[mt][r] + ig*gg;
        c_reg[mt][r] = cn;
        float th = 1.f - 2.f*frcp(1.f + ex2((2.f*L2E)*cn));
        sH[SIDX(1, px+1, ch)] = cvt_bf16(og*th);
      }
    }
    __syncthreads();                      // B3: h_{s+1} visible in LDS
  }

  // ---- policy: logits + 4-way softmax from LDS row 1 --------------------
  {
    int px = t >> 4, s16 = t & 15;
    int base = SIDX(1, px+1, s16*8);
    uint4 h0v = *(const uint4*)&sH[base];
    float la[4] = {0.f,0.f,0.f,0.f};
    const unsigned short* hu = (const unsigned short*)&h0v;
    #pragma unroll
    for (int e=0;e<8;e++){
      int c = s16*8 + e; float hv2 = bf2f(hu[e]);
      const float* w4 = wpol + c*4;
      la[0]+=hv2*w4[0]; la[1]+=hv2*w4[1]; la[2]+=hv2*w4[2]; la[3]+=hv2*w4[3];
    }
    #pragma unroll
    for (int a=0;a<4;a++){
      la[a] += __shfl_xor(la[a], 1, 64);
      la[a] += __shfl_xor(la[a], 2, 64);
      la[a] += __shfl_xor(la[a], 4, 64);
      la[a] += __shfl_xor(la[a], 8, 64);
    }
    if (s16 == 0){
      float m = fmaxf(fmaxf(la[0],la[1]),fmaxf(la[2],la[3]));
      float e[4]; float sum = 0.f;
      #pragma unroll
      for (int a=0;a<4;a++){ e[a]=__expf(la[a]-m); sum+=e[a]; }
      float inv = frcp(sum);
      #pragma unroll
      for (int a=0;a<4;a++){
        int o = ((b*4 + a)*MM + y)*MM + px;
        out[o] = la[a];
        out[65536 + o] = e[a]*inv;
      }
    }
  }
}

extern "C" void kernel_launch(void* const* d_in, const int* in_sizes, int n_in,
                              void* d_out, int out_size, void* d_ws, size_t ws_size,
                              hipStream_t stream){
  const float* mp    = (const float*)d_in[0];
  const float* gl    = (const float*)d_in[1];
  const float* W_hid = (const float*)d_in[2];
  const float* b_hid = (const float*)d_in[3];
  const float* W_h0  = (const float*)d_in[4];
  const float* b_h0  = (const float*)d_in[5];
  const float* W_c0  = (const float*)d_in[6];
  const float* b_c0  = (const float*)d_in[7];
  const float* W_f   = (const float*)d_in[8];
  const float* b_f   = (const float*)d_in[9];
  const float* W_ih  = (const float*)d_in[10];
  const float* b_ih  = (const float*)d_in[11];
  const float* W_hh  = (const float*)d_in[12];
  const float* b_hh  = (const float*)d_in[13];
  const float* W_pol = (const float*)d_in[14];
  float* out = (float*)d_out;

  char* ws = (char*)d_ws;
  unsigned short* whhf  = (unsigned short*)ws;                     // 128 KB
  float*          bsum  = (float*)(ws + (128<<10));                // 4 KB
  unsigned short* wc0   = (unsigned short*)(ws + (132<<10));       // 288 KB
  unsigned short* wc1   = (unsigned short*)(ws + (420<<10));       // 288 KB
  unsigned short* wfbF  = (unsigned short*)(ws + (708<<10));       // 12 KB
  int*            flags = (int*)(ws + (720<<10));                  // 64 KB
  ull*            expbuf= (ull*)(ws + (784<<10));                  // 512 KB

  k_mega<<<NBLK, 512, 0, stream>>>(
      mp, gl, W_hid, b_hid, W_h0, b_h0, W_c0, b_c0, W_f, b_f,
      W_ih, b_ih, W_hh, b_hh, W_pol,
      wc0, wc1, whhf, bsum, wfbF, expbuf, flags, out);
}

// Round 5
// 170.333 us; speedup vs baseline: 1.5013x; 1.0673x over previous
//
#include <hip/hip_runtime.h>

#define MM 32
#define LH 128
#define NSTEPS 15          // K-1
#define SSTR 136
#define NBLK 256           // 2 rows per block, 512 threads (8 waves)
#define FSTR 32
#define SIDX(row,pxi,ch) (((row)*34 + (pxi))*SSTR + (ch))

typedef __bf16  bf16x8  __attribute__((ext_vector_type(8)));
typedef float   floatx4 __attribute__((ext_vector_type(4)));
typedef unsigned long long ull;

#define L2E 1.4426950408889634f

__device__ __forceinline__ float ex2(float x){
#if __has_builtin(__builtin_amdgcn_exp2f)
  return __builtin_amdgcn_exp2f(x);
#else
  float r; asm volatile("v_exp_f32 %0, %1\n\ts_nop 0" : "=v"(r) : "v"(x)); return r;
#endif
}
__device__ __forceinline__ float frcp(float x){ return __builtin_amdgcn_rcpf(x); }

__device__ __forceinline__ unsigned short cvt_bf16(float x){
  __bf16 b = (__bf16)x; unsigned short u; __builtin_memcpy(&u, &b, 2); return u;
}
__device__ __forceinline__ float bf2f(unsigned short u){
  union { unsigned u2; float f; } v; v.u2 = ((unsigned)u) << 16;
  return v.f;
}

// relaxed agent-scope ops (cross-XCD coherent point) — proven transport
__device__ __forceinline__ void st_dev(ull* p, ull v){
  __hip_atomic_store(p, v, __ATOMIC_RELAXED, __HIP_MEMORY_SCOPE_AGENT);
}
__device__ __forceinline__ ull ld_dev(ull* p){
  return __hip_atomic_load(p, __ATOMIC_RELAXED, __HIP_MEMORY_SCOPE_AGENT);
}
// poison-safe relaxed spin (0xAAAAAAAA == far behind under signed diff)
__device__ __forceinline__ void wait_flag(int* f, int target){
  while ((int)(__hip_atomic_load(f, __ATOMIC_RELAXED, __HIP_MEMORY_SCOPE_AGENT) - target) < 0){
    __builtin_amdgcn_s_sleep(1);
  }
}
__device__ __forceinline__ void set_flag(int* f, int v){
  __hip_atomic_store(f, v, __ATOMIC_RELAXED, __HIP_MEMORY_SCOPE_AGENT);
}

// Export buffers: expbuf[parity][blk][64]; slots 0..31 = up-export (conv
// partial for image row y0-1), 32..63 = down-export (row y0+2). Entry packs
// (tag = 2+s)<<32 | f32 bits: tag+payload in one aligned 8B store. Parity
// double-buffer is race-free: producer overwrites parity p at step s+2 only
// after its step-s+1 import, which requires the consumer past its step-s B2.
__global__ __launch_bounds__(512, 2) void k_mega(
    const float* __restrict__ mp,   const float* __restrict__ gl,
    const float* __restrict__ W_hid,const float* __restrict__ b_hid,
    const float* __restrict__ W_h0, const float* __restrict__ b_h0,
    const float* __restrict__ W_c0, const float* __restrict__ b_c0,
    const float* __restrict__ Wf,   const float* __restrict__ bfs,
    const float* __restrict__ wih,  const float* __restrict__ bih,
    const float* __restrict__ Whh,  const float* __restrict__ bhh,
    const float* __restrict__ wpol,
    unsigned short* __restrict__ wc0, unsigned short* __restrict__ wc1,
    unsigned short* __restrict__ whhf, float* __restrict__ bsum,
    unsigned short* __restrict__ wfbF,
    ull* __restrict__ expbuf,
    int* __restrict__ flags, float* __restrict__ out)
{
  __shared__ __attribute__((aligned(16))) unsigned short sH[4*34*SSTR]; // 37 KB
  __shared__ float sCv[6][3][36];     // per-role-wave tap scratch
  __shared__ float sOwn[2][2][32];    // [own row 0/1][part A/B][x]
  __shared__ float sImp[2][32];       // imported neighbor partials (row0,row1)

  int t = threadIdx.x, blk = blockIdx.x;
  int pair = blk & 15, b = blk >> 4;  // row-pair index, image index
  int y0 = pair*2;                    // first image row of the pair
  int wave = t >> 6, l = t & 63, m16 = l & 15, quad = l >> 4;
  bool hasU = (pair > 0), hasD = (pair < 15);
  int ch = wave*16 + m16;             // this wave's 16-ch tile

  // ---- phase P: weight prep into fragment-linear bf16 -------------------
  // W_hh rows are prescaled per-gate by SC[q] (folds log2e into exp2 args).
  for (int c = blk*512 + t; c < 91904; c += NBLK*512){
    if (c < 73728){
      int which = (c >= 36864) ? 1 : 0;
      int cc = which ? c - 36864 : c;
      int i2 = cc*4, frag = i2 >> 9, rem = i2 & 511, ll = rem >> 3, e0 = rem & 7;
      int kk = frag >> 5, ct = (frag >> 2) & 7, kc = frag & 3;
      int co = ct*16 + (ll & 15), ci0 = kc*32 + ((ll >> 4) << 3) + e0;
      const float* src = which ? W_c0 : W_h0;
      ull v = 0;
      #pragma unroll
      for (int j=0;j<4;j++) v |= (ull)cvt_bf16(src[(kk<<14) + (ci0+j)*128 + co]) << (16*j);
      st_dev((ull*)(which ? wc1 : wc0) + cc, v);
    } else if (c < 90112){
      int cc = c - 73728;
      int i2 = cc*4, frag = i2 >> 9, rem = i2 & 511, ll = rem >> 3, e0 = rem & 7;
      int q = frag >> 5, ct = (frag >> 2) & 7, kc = frag & 3;
      float scq = (q == 2) ? (2.f*L2E) : (-L2E);
      int rw = q*128 + ct*16 + (ll & 15), col = kc*32 + ((ll >> 4) << 3) + e0;
      const float* s4 = Whh + rw*128 + col;
      ull v = 0;
      #pragma unroll
      for (int j=0;j<4;j++) v |= (ull)cvt_bf16(s4[j]*scq) << (16*j);
      st_dev((ull*)whhf + cc, v);
    } else if (c < 90368){
      int cc = c - 90112; int j = cc*2;
      union { float f[2]; ull u; } pv;
      pv.f[0] = bih[j] + bhh[j]; pv.f[1] = bih[j+1] + bhh[j+1];
      st_dev((ull*)bsum + cc, pv.u);
    } else {
      // wf B-fragments: frag = ky*4+kc; cols 0..2 = Wf taps (kx), rest zero
      int cc = c - 90368;
      int i2 = cc*4, frag = i2 >> 9, rem = i2 & 511, ll = rem >> 3, e0 = rem & 7;
      int ky = frag >> 2, kc = frag & 3;
      int n = ll & 15, k0 = kc*32 + ((ll >> 4) << 3) + e0;
      ull v = 0;
      if (n < 3){
        #pragma unroll
        for (int j=0;j<4;j++) v |= (ull)cvt_bf16(Wf[(ky*3 + n)*128 + k0 + j]) << (16*j);
      }
      st_dev((ull*)wfbF + cc, v);
    }
  }
  // zero own export slots (both parities): poll tags always defined
  if (t < 128){
    int p = t >> 6, w2 = t & 63;
    st_dev(expbuf + ((size_t)p*NBLK + blk)*64 + w2, 0);
  }
  __syncthreads();                              // vmcnt drained
  if (t == 0) set_flag(&flags[blk*FSTR], 1);

  // ---- phase H: hid rows y0-1..y0+2 computed redundantly into LDS -------
  {
    int hch = t & 127, g = t >> 7;              // LDS row g = image row y0-1+g
    float wz0[9], wz1[9];
    #pragma unroll
    for (int kk=0;kk<9;kk++){ wz0[kk] = W_hid[(kk*2)*LH + hch];
                              wz1[kk] = W_hid[(kk*2+1)*LH + hch]; }
    float bh = b_hid[hch];
    int yi = y0 - 1 + g;
    bool valid = (yi >= 0 && yi < MM);
    for (int x = 0; x < MM; x++){
      float acc2 = 0.f;
      if (valid){
        acc2 = bh;
        #pragma unroll
        for (int ky=0; ky<3; ky++){
          int yy = yi + ky - 1; if (yy < 0 || yy >= MM) continue;
          #pragma unroll
          for (int kx=0; kx<3; kx++){
            int xx = x + kx - 1; if (xx < 0 || xx >= MM) continue;
            int gi = (b*MM + yy)*MM + xx;
            acc2 += mp[gi]*wz0[ky*3+kx] + gl[gi]*wz1[ky*3+kx];
          }
        }
      }
      sH[SIDX(g, x+1, hch)] = cvt_bf16(acc2);
    }
  }
  if (t < 256){   // zero x-halo columns, rows 0..3
    int k = t >> 6, col = ((t >> 5) & 1) ? 33 : 0, c4 = t & 31;
    *(ull*)&sH[SIDX(k, col, c4*4)] = 0;
  }
  // zero the two never-written tap-scratch entries per role wave (once)
  if (t < 6){ sCv[t][0][32] = 0.f; sCv[t][2][1] = 0.f; }
  // grid sync: only prepper blocks' flags (blk<=179)
  if (t < 180) wait_flag(&flags[t*FSTR], 1);
  __syncthreads();

  // ---- h0 & c0 convs: 2 rows (64 px), this wave's 16 out-ch -------------
  float c_reg[4][4];        // [mt][r] — persists across all steps
  {
    floatx4 acch[4], accc[4];
    #pragma unroll
    for (int mt=0;mt<4;mt++){ acch[mt] = (floatx4){0.f,0.f,0.f,0.f};
                              accc[mt] = (floatx4){0.f,0.f,0.f,0.f}; }
    #pragma unroll
    for (int kk=0; kk<9; kk++){
      int ky = kk/3, kx = kk%3;
      #pragma unroll
      for (int kc=0; kc<4; kc++){
        int frag = ((kk*8 + wave)*4 + kc);
        bf16x8 b0 = *(const bf16x8*)(wc0 + (frag << 9) + l*8);
        bf16x8 b1 = *(const bf16x8*)(wc1 + (frag << 9) + l*8);
        #pragma unroll
        for (int mt=0; mt<4; mt++){
          bf16x8 a = *(const bf16x8*)&sH[SIDX((mt>>1)+ky, m16 + (mt&1)*16 + kx, kc*32 + quad*8)];
          acch[mt] = __builtin_amdgcn_mfma_f32_16x16x32_bf16(a, b0, acch[mt], 0,0,0);
          accc[mt] = __builtin_amdgcn_mfma_f32_16x16x32_bf16(a, b1, accc[mt], 0,0,0);
        }
      }
    }
    __syncthreads();                      // all conv reads done
    float bh = b_h0[ch], bc = b_c0[ch];
    #pragma unroll
    for (int mt=0; mt<4; mt++)
      #pragma unroll
      for (int r=0; r<4; r++){
        int px = mt*16 + quad*4 + r;      // 0..63
        c_reg[mt][r] = accc[mt][r] + bc;
        sH[SIDX(1+(px>>5), (px&31)+1, ch)] = cvt_bf16(acch[mt][r] + bh);
      }
  }
  __syncthreads();                        // h0 in LDS rows 1,2

  // W_hh^T fragments cached in registers (64 VGPR — budget is 256 at 2 w/EU)
  bf16x8 bfr[4][4];   // [q][kc]
  #pragma unroll
  for (int q=0;q<4;q++)
    #pragma unroll
    for (int kc=0;kc<4;kc++)
      bfr[q][kc] = *(const bf16x8*)(whhf + (((q*32 + wave*4 + kc) << 9)) + l*8);

  // conv role waves 0..5: (ri = input row 0/1, rky = ky tap 0..2)
  // contribution goes to out row rel = ri + 1 - rky:
  //  w0:(0,0)->own1 A  w1:(1,0)->DOWN  w2:(0,1)->own0 A
  //  w3:(1,1)->own1 B  w4:(0,2)->UP    w5:(1,2)->own0 B
  int ri = wave & 1, rky = wave >> 1;
  bf16x8 wfC[4];
  if (wave < 6){
    #pragma unroll
    for (int kc=0;kc<4;kc++)
      wfC[kc] = *(const bf16x8*)(wfbF + (((rky*4 + kc) << 9) + l*8));
  }
  float wv[4], bs[4];
  #pragma unroll
  for (int q=0;q<4;q++){
    float scq = (q == 2) ? (2.f*L2E) : (-L2E);
    int g = q*128 + ch;
    wv[q] = wih[g]*scq; bs[q] = bsum[g]*scq;
  }
  float bf0 = bfs[0];

  // ---- 15 LSTM steps ----------------------------------------------------
  for (int s = 0; s < NSTEPS; s++){
    int cur = s & 1;

    // P1: role waves compute their conv-row contribution, tap-sum in private
    // LDS scratch, publish/store IMMEDIATELY (no barrier before publish).
    if (wave < 6){
      bool isExp = (wave == 1) || (wave == 4);
      bool doit = !isExp || (wave == 1 ? hasD : hasU);
      if (doit){
        if (isExp) __builtin_amdgcn_s_setprio(1);
        floatx4 p0 = (floatx4){0.f,0.f,0.f,0.f};
        floatx4 p1 = (floatx4){0.f,0.f,0.f,0.f};
        #pragma unroll
        for (int kc=0;kc<4;kc++){
          bf16x8 aL = *(const bf16x8*)&sH[SIDX(1+ri, m16 + 1,  kc*32 + quad*8)];
          bf16x8 aR = *(const bf16x8*)&sH[SIDX(1+ri, m16 + 17, kc*32 + quad*8)];
          p0 = __builtin_amdgcn_mfma_f32_16x16x32_bf16(aL, wfC[kc], p0, 0,0,0);
          p1 = __builtin_amdgcn_mfma_f32_16x16x32_bf16(aR, wfC[kc], p1, 0,0,0);
        }
        // P[px][tap] -> scratch[tap][px+tap]; all taps of out[x] at idx x+1
        if (m16 < 3){
          #pragma unroll
          for (int r=0;r<4;r++){
            sCv[wave][m16][quad*4 + r + m16]      = p0[r];
            sCv[wave][m16][16 + quad*4 + r + m16] = p1[r];
          }
        }
        __asm__ __volatile__("" ::: "memory");  // same-wave DS in-order
        if (l < 32){
          float v = sCv[wave][0][l+1] + sCv[wave][1][l+1] + sCv[wave][2][l+1];
          if (wave == 1 || wave == 4){
            union { float f; unsigned u; } pv; pv.f = v;
            ull pk = ((ull)(unsigned)(2 + s) << 32) | (ull)pv.u;
            st_dev(expbuf + ((size_t)cur*NBLK + blk)*64 + (wave == 1 ? 32 : 0) + l, pk);
          } else if (wave == 0){
            sOwn[1][0][l] = bf0 + v;
          } else if (wave == 2){
            sOwn[0][0][l] = bf0 + v;
          } else if (wave == 3){
            sOwn[1][1][l] = v;
          } else {             // wave 5
            sOwn[0][1][l] = v;
          }
        }
        if (isExp) __builtin_amdgcn_s_setprio(0);
      }
    }

    // gates GEMM on own rows (LDS rows 1,2), B from registers
    floatx4 acc[4][4];    // [mt][q]
    #pragma unroll
    for (int mt=0;mt<4;mt++)
      #pragma unroll
      for (int q=0;q<4;q++) acc[mt][q] = (floatx4){0.f,0.f,0.f,0.f};
    #pragma unroll
    for (int kc=0; kc<4; kc++){
      bf16x8 a[4];
      #pragma unroll
      for (int mt=0;mt<4;mt++)
        a[mt] = *(const bf16x8*)&sH[SIDX(1+(mt>>1), m16 + (mt&1)*16 + 1, kc*32 + quad*8)];
      #pragma unroll
      for (int q=0; q<4; q++)
        #pragma unroll
        for (int mt=0; mt<4; mt++)
          acc[mt][q] = __builtin_amdgcn_mfma_f32_16x16x32_bf16(a[mt], bfr[q][kc], acc[mt][q], 0,0,0);
    }

    // wave 7: import both neighbors in parallel, 2-deep pipelined poll
    if (wave == 7){
      int d = l >> 5, x = l & 31;
      bool ok = d ? hasD : hasU;
      float v = 0.f;
      if (ok){
        ull* p = expbuf + ((size_t)cur*NBLK + (d ? blk+1 : blk-1))*64 + (d ? 0 : 32) + x;
        unsigned tgt = (unsigned)(2 + s);
        ull c0 = ld_dev(p);
        ull c1 = ld_dev(p);
        while ((int)((unsigned)(c0 >> 32) - tgt) < 0){
          c0 = c1;
          c1 = ld_dev(p);
        }
        union { unsigned u; float f; } pv; pv.u = (unsigned)c0; v = pv.f;
      }
      sImp[d][x] = v;
    }
    __syncthreads();                      // B2: sOwn/sImp final, row reads done

    // LSTM pointwise epilogue (exp2-form, prescaled gates; rcp not IEEE div)
    #pragma unroll
    for (int mt=0; mt<4; mt++){
      int row = mt >> 1;
      #pragma unroll
      for (int r=0; r<4; r++){
        int x = ((mt & 1) << 4) + quad*4 + r;     // px & 31
        float iv = sOwn[row][0][x] + sOwn[row][1][x] + sImp[row][x];
        float p0 = acc[mt][0][r] + iv*wv[0] + bs[0];
        float p1 = acc[mt][1][r] + iv*wv[1] + bs[1];
        float p2 = acc[mt][2][r] + iv*wv[2] + bs[2];
        float p3 = acc[mt][3][r] + iv*wv[3] + bs[3];
        float ig = frcp(1.f + ex2(p0));
        float fg = frcp(1.f + ex2(p1));
        float gg = 1.f - 2.f*frcp(1.f + ex2(p2));
        float og = frcp(1.f + ex2(p3));
        float cn = fg*c_reg[mt][r] + ig*gg;
        c_reg[mt][r] = cn;
        float th = 1.f - 2.f*frcp(1.f + ex2((2.f*L2E)*cn));
        sH[SIDX(1+row, x+1, ch)] = cvt_bf16(og*th);
      }
    }
    __syncthreads();                      // B3: h_{s+1} visible in LDS
  }

  // ---- policy: logits + 4-way softmax from LDS rows 1,2 -----------------
  {
    int px = t >> 3, s8 = t & 7;
    int base = SIDX(1+(px>>5), (px&31)+1, s8*16);
    uint4 h0v = *(const uint4*)&sH[base];
    uint4 h1v = *(const uint4*)&sH[base + 8];
    float la[4] = {0.f,0.f,0.f,0.f};
    const unsigned short* hu = (const unsigned short*)&h0v;
    #pragma unroll
    for (int e=0;e<8;e++){
      int c = s8*16 + e; float hv2 = bf2f(hu[e]);
      const float* w4 = wpol + c*4;
      la[0]+=hv2*w4[0]; la[1]+=hv2*w4[1]; la[2]+=hv2*w4[2]; la[3]+=hv2*w4[3];
    }
    hu = (const unsigned short*)&h1v;
    #pragma unroll
    for (int e=0;e<8;e++){
      int c = s8*16 + 8 + e; float hv2 = bf2f(hu[e]);
      const float* w4 = wpol + c*4;
      la[0]+=hv2*w4[0]; la[1]+=hv2*w4[1]; la[2]+=hv2*w4[2]; la[3]+=hv2*w4[3];
    }
    #pragma unroll
    for (int a=0;a<4;a++){
      la[a] += __shfl_xor(la[a], 1, 64);
      la[a] += __shfl_xor(la[a], 2, 64);
      la[a] += __shfl_xor(la[a], 4, 64);
    }
    if (s8 == 0){
      int y = y0 + (px>>5), x = px & 31;
      float m = fmaxf(fmaxf(la[0],la[1]),fmaxf(la[2],la[3]));
      float e[4]; float sum = 0.f;
      #pragma unroll
      for (int a=0;a<4;a++){ e[a]=__expf(la[a]-m); sum+=e[a]; }
      float inv = frcp(sum);
      #pragma unroll
      for (int a=0;a<4;a++){
        int o = ((b*4 + a)*MM + y)*MM + x;
        out[o] = la[a];
        out[65536 + o] = e[a]*inv;
      }
    }
  }
}

extern "C" void kernel_launch(void* const* d_in, const int* in_sizes, int n_in,
                              void* d_out, int out_size, void* d_ws, size_t ws_size,
                              hipStream_t stream){
  const float* mp    = (const float*)d_in[0];
  const float* gl    = (const float*)d_in[1];
  const float* W_hid = (const float*)d_in[2];
  const float* b_hid = (const float*)d_in[3];
  const float* W_h0  = (const float*)d_in[4];
  const float* b_h0  = (const float*)d_in[5];
  const float* W_c0  = (const float*)d_in[6];
  const float* b_c0  = (const float*)d_in[7];
  const float* W_f   = (const float*)d_in[8];
  const float* b_f   = (const float*)d_in[9];
  const float* W_ih  = (const float*)d_in[10];
  const float* b_ih  = (const float*)d_in[11];
  const float* W_hh  = (const float*)d_in[12];
  const float* b_hh  = (const float*)d_in[13];
  const float* W_pol = (const float*)d_in[14];
  float* out = (float*)d_out;

  char* ws = (char*)d_ws;
  unsigned short* whhf  = (unsigned short*)ws;                     // 128 KB
  float*          bsum  = (float*)(ws + (128<<10));                // 4 KB
  unsigned short* wc0   = (unsigned short*)(ws + (132<<10));       // 288 KB
  unsigned short* wc1   = (unsigned short*)(ws + (420<<10));       // 288 KB
  unsigned short* wfbF  = (unsigned short*)(ws + (708<<10));       // 12 KB
  int*            flags = (int*)(ws + (720<<10));                  // 64 KB
  ull*            expbuf= (ull*)(ws + (784<<10));                  // 256 KB

  k_mega<<<NBLK, 512, 0, stream>>>(
      mp, gl, W_hid, b_hid, W_h0, b_h0, W_c0, b_c0, W_f, b_f,
      W_ih, b_ih, W_hh, b_hh, W_pol,
      wc0, wc1, whhf, bsum, wfbF, expbuf, flags, out);
}